// Round 1
// baseline (3852.835 us; speedup 1.0000x reference)
//
#include <hip/hip_runtime.h>
#include <math.h>

#define HDIM 256
#define DTc 0.03f
#define ALPHAc 0.9f

// ---------------------------------------------------------------------------
// One recurrence step:
//   pre[i,j] = W[j]*x[i,j] + sum_k V[i,k]*x[j,k] + b[j]
//   z[i,j]  -= DT*(tanh(pre) + ALPHA*x[i,j])
//   x_out    = x[i,j] + DT*z[i,j]
// Tile: 32 rows(i) x 16 cols(j) per WG -> grid (16 j-tiles, 8 i-tiles) = 128 WGs.
// x rows [tile_j, tile_j+16) staged in LDS (B-operand of V@x^T).
// V rows streamed from global (L2-resident, 4 MB/step total).
// Double-buffered x (x_in read-only, x_out written) -> no intra-step race.
// ---------------------------------------------------------------------------
__global__ __launch_bounds__(256) void unicornn_step(
    const float* __restrict__ x_in, float* __restrict__ x_out,
    float* __restrict__ z, const float* __restrict__ V,
    const float* __restrict__ W, const float* __restrict__ b, int first)
{
    __shared__ float Xs[16][260];   // stride 260: 2-way conflicts only (free)
    const int t = threadIdx.x;
    const int tile_i = blockIdx.y << 5;   // 8 i-tiles * 32
    const int tile_j = blockIdx.x << 4;   // 16 j-tiles * 16

    // stage x_in rows [tile_j, tile_j+16): 16*256 floats = 1024 float4
    {
        const float4* Xg = (const float4*)(x_in + tile_j * HDIM);
#pragma unroll
        for (int r = 0; r < 4; ++r) {
            int idx = t + (r << 8);     // 0..1023
            int row = idx >> 6;         // 64 float4 per row
            int q = idx & 63;
            *((float4*)&Xs[row][q << 2]) = Xg[idx];
        }
    }
    __syncthreads();

    const int ti = t >> 4;   // 0..15
    const int tj = t & 15;   // 0..15
    const int gi0 = tile_i + ti, gi1 = gi0 + 16;
    const int gj = tile_j + tj;

    const float4* Vg0 = (const float4*)(V + gi0 * HDIM);
    const float4* Vg1 = (const float4*)(V + gi1 * HDIM);
    float acc0 = 0.f, acc1 = 0.f;
#pragma unroll 8
    for (int kq = 0; kq < 64; ++kq) {
        float4 xb = *(const float4*)&Xs[tj][kq << 2];
        float4 v0 = Vg0[kq];
        float4 v1 = Vg1[kq];
        acc0 = fmaf(v0.x, xb.x, acc0);
        acc0 = fmaf(v0.y, xb.y, acc0);
        acc0 = fmaf(v0.z, xb.z, acc0);
        acc0 = fmaf(v0.w, xb.w, acc0);
        acc1 = fmaf(v1.x, xb.x, acc1);
        acc1 = fmaf(v1.y, xb.y, acc1);
        acc1 = fmaf(v1.z, xb.z, acc1);
        acc1 = fmaf(v1.w, xb.w, acc1);
    }

    const float Wj = W[gj];
    const float bj = b[gj];
    {
        float xv = x_in[gi0 * HDIM + gj];
        float pre = fmaf(Wj, xv, acc0) + bj;
        float zv = first ? 0.f : z[gi0 * HDIM + gj];
        zv -= DTc * (tanhf(pre) + ALPHAc * xv);
        z[gi0 * HDIM + gj] = zv;
        x_out[gi0 * HDIM + gj] = fmaf(DTc, zv, xv);
    }
    {
        float xv = x_in[gi1 * HDIM + gj];
        float pre = fmaf(Wj, xv, acc1) + bj;
        float zv = first ? 0.f : z[gi1 * HDIM + gj];
        zv -= DTc * (tanhf(pre) + ALPHAc * xv);
        z[gi1 * HDIM + gj] = zv;
        x_out[gi1 * HDIM + gj] = fmaf(DTc, zv, xv);
    }
}

// ---------------------------------------------------------------------------
// C[i][j] = sum_k A[i][k]*B[j][k] + bias[j]   (A: M x K, B: N x K, C: M x N)
// Tile 32x32, 2x2 per thread. grid = (N/32, M/32), block 256.
// Runs twice total (input/output layers) - simplicity over speed.
// ---------------------------------------------------------------------------
__global__ __launch_bounds__(256) void gemm_bt_bias(
    const float* __restrict__ A, const float* __restrict__ B,
    const float* __restrict__ bias, float* __restrict__ C, int N, int K)
{
    __shared__ float As[32][260];
    __shared__ float Bs[32][260];
    const int t = threadIdx.x;
    const int i_base = blockIdx.y << 5;
    const int j_base = blockIdx.x << 5;
    const int kq = K >> 2;           // float4 per row
    const int total = 32 * kq;
    const float4* Ag = (const float4*)(A + i_base * K);
    const float4* Bg = (const float4*)(B + j_base * K);
    for (int idx = t; idx < total; idx += 256) {
        int row = idx / kq, q = idx % kq;
        *((float4*)&As[row][q << 2]) = Ag[idx];
        *((float4*)&Bs[row][q << 2]) = Bg[idx];
    }
    __syncthreads();

    const int ti = t >> 4, tj = t & 15;
    float a00 = 0.f, a01 = 0.f, a10 = 0.f, a11 = 0.f;
    for (int k = 0; k < K; k += 4) {
        float4 a0 = *(const float4*)&As[ti][k];
        float4 a1 = *(const float4*)&As[ti + 16][k];
        float4 b0 = *(const float4*)&Bs[tj][k];
        float4 b1 = *(const float4*)&Bs[tj + 16][k];
        a00 = fmaf(a0.x, b0.x, a00); a00 = fmaf(a0.y, b0.y, a00);
        a00 = fmaf(a0.z, b0.z, a00); a00 = fmaf(a0.w, b0.w, a00);
        a01 = fmaf(a0.x, b1.x, a01); a01 = fmaf(a0.y, b1.y, a01);
        a01 = fmaf(a0.z, b1.z, a01); a01 = fmaf(a0.w, b1.w, a01);
        a10 = fmaf(a1.x, b0.x, a10); a10 = fmaf(a1.y, b0.y, a10);
        a10 = fmaf(a1.z, b0.z, a10); a10 = fmaf(a1.w, b0.w, a10);
        a11 = fmaf(a1.x, b1.x, a11); a11 = fmaf(a1.y, b1.y, a11);
        a11 = fmaf(a1.z, b1.z, a11); a11 = fmaf(a1.w, b1.w, a11);
    }
    const int gi0 = i_base + ti, gi1 = gi0 + 16;
    const int gj0 = j_base + tj, gj1 = gj0 + 16;
    C[gi0 * N + gj0] = a00 + bias[gj0];
    C[gi0 * N + gj1] = a01 + bias[gj1];
    C[gi1 * N + gj0] = a10 + bias[gj0];
    C[gi1 * N + gj1] = a11 + bias[gj1];
}

extern "C" void kernel_launch(void* const* d_in, const int* in_sizes, int n_in,
                              void* d_out, int out_size, void* d_ws, size_t ws_size,
                              hipStream_t stream) {
    const float* x     = (const float*)d_in[0];   // [256,128]
    const float* w_in  = (const float*)d_in[1];   // [256,128]
    const float* b_in  = (const float*)d_in[2];   // [256]
    const float* w_rec = (const float*)d_in[3];   // [2,256]
    const float* v_rec = (const float*)d_in[4];   // [2,256,256]
    const float* b_rec = (const float*)d_in[5];   // [2,256]
    const float* w_out = (const float*)d_in[6];   // [128,256]
    const float* b_out = (const float*)d_in[7];   // [128]
    float* out = (float*)d_out;                   // [256,128]

    float* buf0 = (float*)d_ws;          // 256*256 floats
    float* buf1 = buf0 + HDIM * HDIM;
    float* zbuf = buf1 + HDIM * HDIM;

    // input layer: h = x @ w_in^T + b_in  -> buf0   (M=256,N=256,K=128)
    gemm_bt_bias<<<dim3(8, 8), 256, 0, stream>>>(x, w_in, b_in, buf0, 256, 128);

    float* cur = buf0;
    float* nxt = buf1;
    for (int l = 0; l < 2; ++l) {
        const float* V = v_rec + l * HDIM * HDIM;
        const float* W = w_rec + l * HDIM;
        const float* bb = b_rec + l * HDIM;
        for (int s = 0; s < HDIM; ++s) {
            unicornn_step<<<dim3(16, 8), 256, 0, stream>>>(cur, nxt, zbuf, V, W, bb, s == 0);
            float* tmp = cur; cur = nxt; nxt = tmp;
        }
    }

    // output layer: out = h @ w_out^T + b_out  (M=256,N=128,K=256)
    gemm_bt_bias<<<dim3(4, 8), 256, 0, stream>>>(cur, w_out, b_out, out, 128, 256);
}